// Round 1
// baseline (1094.190 us; speedup 1.0000x reference)
//
#include <hip/hip_runtime.h>

#define HID 256
#define LAT 128
#define VOC 32000
#define NSTEP 128

// ---------------- encoder: one kernel launch per tree level ----------------
// h[i] (internal nodes 0..254) = [emb_i, h_left, h_right] @ Wpar.T + bpar
// leaves (255..510) are just emb rows, consumed directly by level-7 blocks.
__global__ void enc_level(const float* __restrict__ embed, const int* __restrict__ values,
                          const float* __restrict__ Wpar, const float* __restrict__ bpar,
                          float* __restrict__ h, int base, int leafchild) {
    const int i = base + blockIdx.x;
    const int t = threadIdx.x;             // 0..255
    __shared__ float cat[768];
    cat[t] = embed[(size_t)values[i] * HID + t];
    const int c1 = 2 * i + 1, c2 = 2 * i + 2;
    if (leafchild) {
        cat[256 + t] = embed[(size_t)values[c1] * HID + t];
        cat[512 + t] = embed[(size_t)values[c2] * HID + t];
    } else {
        cat[256 + t] = h[c1 * HID + t];
        cat[512 + t] = h[c2 * HID + t];
    }
    __syncthreads();
    float acc = bpar[t];
    const float4* wr = (const float4*)(Wpar + (size_t)t * 768);
    const float4* cf = (const float4*)cat;
#pragma unroll 8
    for (int k = 0; k < 192; k++) {
        float4 w = wr[k], c = cf[k];
        acc += w.x * c.x + w.y * c.y + w.z * c.z + w.w * c.w;
    }
    h[i * HID + t] = acc;
}

// ---------------- root head: mu, logvar, z ----------------
__global__ void root_kernel(const float* __restrict__ h,
                            const float* __restrict__ Wmu, const float* __restrict__ bmu,
                            const float* __restrict__ Wlv, const float* __restrict__ blv,
                            const float* __restrict__ eps,
                            float* __restrict__ out, float* __restrict__ z) {
    const int t = threadIdx.x;             // 0..127
    __shared__ float root_s[256];
    root_s[t] = h[t];
    root_s[128 + t] = h[128 + t];
    __syncthreads();
    float am = bmu[t], al = blv[t];
    const float4* wm = (const float4*)(Wmu + (size_t)t * HID);
    const float4* wl = (const float4*)(Wlv + (size_t)t * HID);
    const float4* r4 = (const float4*)root_s;
#pragma unroll 8
    for (int k = 0; k < 64; k++) {
        float4 r = r4[k];
        float4 a = wm[k], b = wl[k];
        am += a.x * r.x + a.y * r.y + a.z * r.z + a.w * r.w;
        al += b.x * r.x + b.y * r.y + b.z * r.z + b.w * r.w;
    }
    out[(size_t)NSTEP * VOC + t] = am;
    out[(size_t)NSTEP * VOC + 128 + t] = al;
    z[t] = am + eps[t] * expf(0.5f * al);
}

// ---------------- precompute Wcomb = Wp_tail @ W2[1:], bcomb ----------------
__global__ void wcomb_kernel(const float* __restrict__ Wp, const float* __restrict__ W2,
                             const float* __restrict__ b2, const float* __restrict__ bp,
                             float* __restrict__ Wcomb, float* __restrict__ bcomb) {
    const int o = blockIdx.x;              // 0..255
    const int k = threadIdx.x;             // 0..255
    const float* wpt = Wp + (size_t)(VOC + o) * HID;
    float acc = 0.f;
    for (int j = 0; j < 256; j++)
        acc += wpt[j] * W2[(size_t)(1 + j) * HID + k];
    Wcomb[o * HID + k] = acc;
    if (k == 0) {
        float b = bp[VOC + o];
        for (int j = 0; j < 256; j++) b += wpt[j] * b2[1 + j];
        bcomb[o] = b;
    }
}

// ---------------- sequential decoder recurrence: ONE block, weights in regs ----------------
__global__ __launch_bounds__(512, 2)
void recur_kernel(const float* __restrict__ W1, const float* __restrict__ b1,
                  const float* __restrict__ W2, const float* __restrict__ b2,
                  const float* __restrict__ Wcomb, const float* __restrict__ bcomb,
                  const float* __restrict__ z,
                  float* __restrict__ Hrec, int* __restrict__ rowflag) {
    const int t = threadIdx.x;
    const int o = t & 255;
    const int half = t >> 8;               // 0 or 1
    __shared__ float stack_s[64 * 128];    // 32 KB
    __shared__ float hmid_s[256];
    __shared__ float part_s[2 * 256];
    __shared__ float w2r0_s[256];
    __shared__ float b1_s[256];
    __shared__ float bcomb_s[256];
    __shared__ float c0red_s[64];
    __shared__ int sp_s, op_s, par_s;

    // resident weights (registers)
    float w1r[64];
    const float* w1p = W1 + (size_t)o * 128 + half * 64;
#pragma unroll
    for (int j = 0; j < 64; j++) w1r[j] = w1p[j];
    float wcr[128];
    const float* wcp = Wcomb + (size_t)o * 256 + half * 128;
#pragma unroll
    for (int j = 0; j < 128; j++) wcr[j] = wcp[j];

    if (half == 0) { w2r0_s[o] = W2[o]; b1_s[o] = b1[o]; bcomb_s[o] = bcomb[o]; }
    if (t < 128) { stack_s[t] = z[t]; rowflag[t] = -1; }
    if (t == 0) { sp_s = 1; op_s = 0; }
    float b20 = b2[0];
    __syncthreads();

    for (int step = 0; step < NSTEP; step++) {
        const int sp = sp_s, op = op_s;
        const bool active = sp > 0;
        const int idx = active ? sp - 1 : 0;

        // phase 1: hmid = lrelu(W1 @ node + b1)
        const float* nodep = stack_s + idx * 128 + half * 64;
        float a = 0.f;
#pragma unroll
        for (int j = 0; j < 64; j++) a += w1r[j] * nodep[j];
        part_s[half * 256 + o] = a;
        __syncthreads();
        if (half == 0) {
            float pre = part_s[o] + part_s[256 + o] + b1_s[o];
            hmid_s[o] = pre > 0.f ? pre : 0.2f * pre;
        }
        __syncthreads();

        // c0 partials (branch decision dot)
        if (t < 64) {
            float s = 0.f;
#pragma unroll
            for (int m = 0; m < 4; m++) s += w2r0_s[t * 4 + m] * hmid_s[t * 4 + m];
            c0red_s[t] = s;
        }
        // record hmid for the batched vocab GEMM
        if (half == 0 && active) Hrec[(size_t)op * HID + o] = hmid_s[o];
        // phase 2: [ll;rl] = Wcomb @ hmid + bcomb (used only if parent)
        float a2 = 0.f;
        const float* hp = hmid_s + half * 128;
#pragma unroll
        for (int j = 0; j < 128; j++) a2 += wcr[j] * hp[j];
        part_s[half * 256 + o] = a2;
        __syncthreads();

        if (t == 0) {
            float c0 = b20;
            for (int m = 0; m < 64; m++) c0 += c0red_s[m];
            const int par = (c0 > 0.f) && (sp <= 63) && active;
            par_s = par;
            if (active) rowflag[op] = par;
            sp_s = active ? (par ? sp + 1 : sp - 1) : sp;
            op_s = op + (active ? 1 : 0);
        }
        __syncthreads();

        if (par_s && half == 0) {
            float v = part_s[o] + part_s[256 + o] + bcomb_s[o];
            stack_s[(idx + (o >> 7)) * 128 + (o & 127)] = v;   // ll -> idx, rl -> idx+1
        }
        __syncthreads();
    }
}

// ---------------- Co1 = Hrec @ W2[1:].T + b2[1:] ----------------
__global__ void co1_kernel(const float* __restrict__ Hrec, const float* __restrict__ W2,
                           const float* __restrict__ b2, float* __restrict__ Co1) {
    const int r = blockIdx.x;              // 0..127
    const int c = threadIdx.x;             // 0..255
    __shared__ float hs[256];
    hs[c] = Hrec[(size_t)r * HID + c];
    __syncthreads();
    float acc = b2[1 + c];
    const float4* w = (const float4*)(W2 + (size_t)(1 + c) * HID);
    const float4* h4 = (const float4*)hs;
#pragma unroll 8
    for (int k = 0; k < 64; k++) {
        float4 a = w[k], b = h4[k];
        acc += a.x * b.x + a.y * b.y + a.z * b.z + a.w * b.w;
    }
    Co1[r * HID + c] = acc;
}

// ---------------- zero unused out rows ----------------
__global__ void zero_rows(const int* __restrict__ rowflag, float* __restrict__ out) {
    const int r = blockIdx.x;
    if (rowflag[r] != -1) return;
    for (int q = threadIdx.x; q < VOC; q += 256) out[(size_t)r * VOC + q] = 0.f;
}

// ---------------- batched vocab matvecs: out[r] = Co1[r] @ Wx.T + bx ----------------
__global__ void value_kernel(const float* __restrict__ Co1, const int* __restrict__ rowflag,
                             const float* __restrict__ Wl, const float* __restrict__ bl,
                             const float* __restrict__ Wp, const float* __restrict__ bp,
                             float* __restrict__ out) {
    const int m = blockIdx.y;              // 0 = leaf (Wl), 1 = parent (Wp)
    const int t = threadIdx.x;
    const int v0 = blockIdx.x * 512 + t;
    const int v1 = v0 + 256;
    const bool ok1 = v1 < VOC;
    const float* Wx = m ? Wp : Wl;
    const float* bx = m ? bp : bl;
    __shared__ int list[128];
    __shared__ int nrows_s;
    __shared__ float co_s[32 * 256];       // 32 KB
    if (t == 0) {
        int n = 0;
        for (int r = 0; r < 128; r++) if (rowflag[r] == m) list[n++] = r;
        nrows_s = n;
    }
    __syncthreads();
    const int nrows = nrows_s;
    const float4* wa4 = (const float4*)(Wx + (size_t)v0 * HID);
    const float4* wb4 = ok1 ? (const float4*)(Wx + (size_t)v1 * HID) : wa4;

    for (int cs = 0; cs < nrows; cs += 32) {
        for (int q = t; q < 32 * 256; q += 256) {
            int rr = q >> 8, k = q & 255;
            co_s[q] = (cs + rr < nrows) ? Co1[(size_t)list[cs + rr] * HID + k] : 0.f;
        }
        __syncthreads();
        float acc0[32], acc1[32];
#pragma unroll
        for (int rr = 0; rr < 32; rr++) { acc0[rr] = 0.f; acc1[rr] = 0.f; }
        for (int k4 = 0; k4 < 64; k4++) {
            float4 wa = wa4[k4];
            float4 wb = wb4[k4];
#pragma unroll
            for (int rr = 0; rr < 32; rr++) {
                float4 c = ((const float4*)co_s)[rr * 64 + k4];
                acc0[rr] += c.x * wa.x + c.y * wa.y + c.z * wa.z + c.w * wa.w;
                acc1[rr] += c.x * wb.x + c.y * wb.y + c.z * wb.z + c.w * wb.w;
            }
        }
        const int nr = min(32, nrows - cs);
        for (int rr = 0; rr < nr; rr++) {
            const int row = list[cs + rr];
            out[(size_t)row * VOC + v0] = acc0[rr] + bx[v0];
            if (ok1) out[(size_t)row * VOC + v1] = acc1[rr] + bx[v1];
        }
        __syncthreads();
    }
}

extern "C" void kernel_launch(void* const* d_in, const int* in_sizes, int n_in,
                              void* d_out, int out_size, void* d_ws, size_t ws_size,
                              hipStream_t stream) {
    const float* embed = (const float*)d_in[0];
    const float* Wpar  = (const float*)d_in[1];
    const float* bpar  = (const float*)d_in[2];
    const float* Wmu   = (const float*)d_in[3];
    const float* bmu   = (const float*)d_in[4];
    const float* Wlv   = (const float*)d_in[5];
    const float* blv   = (const float*)d_in[6];
    const float* W1    = (const float*)d_in[7];
    const float* b1    = (const float*)d_in[8];
    const float* W2    = (const float*)d_in[9];
    const float* b2    = (const float*)d_in[10];
    const float* Wl    = (const float*)d_in[11];
    const float* bl    = (const float*)d_in[12];
    const float* Wp    = (const float*)d_in[13];
    const float* bp    = (const float*)d_in[14];
    const float* eps   = (const float*)d_in[15];
    const int*  values = (const int*)d_in[16];

    float* ws = (float*)d_ws;
    float* h      = ws;                    // 255*256 = 65280
    float* z      = ws + 65280;            // 128
    float* Wcomb  = ws + 65408;            // 65536
    float* bcomb  = ws + 130944;           // 256
    float* Hrec   = ws + 131200;           // 128*256 = 32768
    float* Co1    = ws + 163968;           // 32768
    int*   rowflag = (int*)(ws + 196736);  // 128
    float* out = (float*)d_out;

    // precompute collapsed push-weights (independent of encoder)
    wcomb_kernel<<<256, 256, 0, stream>>>(Wp, W2, b2, bp, Wcomb, bcomb);

    // encoder, level by level (7 .. 0)
    enc_level<<<128, 256, 0, stream>>>(embed, values, Wpar, bpar, h, 127, 1);
    enc_level<<< 64, 256, 0, stream>>>(embed, values, Wpar, bpar, h, 63, 0);
    enc_level<<< 32, 256, 0, stream>>>(embed, values, Wpar, bpar, h, 31, 0);
    enc_level<<< 16, 256, 0, stream>>>(embed, values, Wpar, bpar, h, 15, 0);
    enc_level<<<  8, 256, 0, stream>>>(embed, values, Wpar, bpar, h, 7, 0);
    enc_level<<<  4, 256, 0, stream>>>(embed, values, Wpar, bpar, h, 3, 0);
    enc_level<<<  2, 256, 0, stream>>>(embed, values, Wpar, bpar, h, 1, 0);
    enc_level<<<  1, 256, 0, stream>>>(embed, values, Wpar, bpar, h, 0, 0);

    root_kernel<<<1, 128, 0, stream>>>(h, Wmu, bmu, Wlv, blv, eps, out, z);

    recur_kernel<<<1, 512, 0, stream>>>(W1, b1, W2, b2, Wcomb, bcomb, z, Hrec, rowflag);

    co1_kernel<<<128, 256, 0, stream>>>(Hrec, W2, b2, Co1);
    zero_rows<<<128, 256, 0, stream>>>(rowflag, out);
    value_kernel<<<dim3(63, 2), 256, 0, stream>>>(Co1, rowflag, Wl, bl, Wp, bp, out);
}

// Round 2
// 709.956 us; speedup vs baseline: 1.5412x; 1.5412x over previous
//
#include <hip/hip_runtime.h>

#define HID 256
#define LAT 128
#define VOC 32000
#define NSTEP 128

// ---------------- encoder: one kernel launch per tree level ----------------
__global__ void enc_level(const float* __restrict__ embed, const int* __restrict__ values,
                          const float* __restrict__ Wpar, const float* __restrict__ bpar,
                          float* __restrict__ h, int base, int leafchild) {
    const int i = base + blockIdx.x;
    const int t = threadIdx.x;             // 0..255
    __shared__ float cat[768];
    cat[t] = embed[(size_t)values[i] * HID + t];
    const int c1 = 2 * i + 1, c2 = 2 * i + 2;
    if (leafchild) {
        cat[256 + t] = embed[(size_t)values[c1] * HID + t];
        cat[512 + t] = embed[(size_t)values[c2] * HID + t];
    } else {
        cat[256 + t] = h[c1 * HID + t];
        cat[512 + t] = h[c2 * HID + t];
    }
    __syncthreads();
    float acc = bpar[t];
    const float4* wr = (const float4*)(Wpar + (size_t)t * 768);
    const float4* cf = (const float4*)cat;
#pragma unroll 8
    for (int k = 0; k < 192; k++) {
        float4 w = wr[k], c = cf[k];
        acc += w.x * c.x + w.y * c.y + w.z * c.z + w.w * c.w;
    }
    h[i * HID + t] = acc;
}

// ---------------- root head: mu, logvar, z ----------------
__global__ void root_kernel(const float* __restrict__ h,
                            const float* __restrict__ Wmu, const float* __restrict__ bmu,
                            const float* __restrict__ Wlv, const float* __restrict__ blv,
                            const float* __restrict__ eps,
                            float* __restrict__ out, float* __restrict__ z) {
    const int t = threadIdx.x;             // 0..127
    __shared__ float root_s[256];
    root_s[t] = h[t];
    root_s[128 + t] = h[128 + t];
    __syncthreads();
    float am = bmu[t], al = blv[t];
    const float4* wm = (const float4*)(Wmu + (size_t)t * HID);
    const float4* wl = (const float4*)(Wlv + (size_t)t * HID);
    const float4* r4 = (const float4*)root_s;
#pragma unroll 8
    for (int k = 0; k < 64; k++) {
        float4 r = r4[k];
        float4 a = wm[k], b = wl[k];
        am += a.x * r.x + a.y * r.y + a.z * r.z + a.w * r.w;
        al += b.x * r.x + b.y * r.y + b.z * r.z + b.w * r.w;
    }
    out[(size_t)NSTEP * VOC + t] = am;
    out[(size_t)NSTEP * VOC + 128 + t] = al;
    z[t] = am + eps[t] * expf(0.5f * al);
}

// ---------------- precompute Wcomb = Wp_tail @ W2[1:], bcomb ----------------
__global__ void wcomb_kernel(const float* __restrict__ Wp, const float* __restrict__ W2,
                             const float* __restrict__ b2, const float* __restrict__ bp,
                             float* __restrict__ Wcomb, float* __restrict__ bcomb) {
    const int o = blockIdx.x;              // 0..255
    const int k = threadIdx.x;             // 0..255
    const float* wpt = Wp + (size_t)(VOC + o) * HID;
    float acc = 0.f;
    for (int j = 0; j < 256; j++)
        acc += wpt[j] * W2[(size_t)(1 + j) * HID + k];
    Wcomb[o * HID + k] = acc;
    if (k == 0) {
        float b = bp[VOC + o];
        for (int j = 0; j < 256; j++) b += wpt[j] * b2[1 + j];
        bcomb[o] = b;
    }
}

// ---------------- sequential decoder recurrence: ONE block, weights in regs ----------------
// sp/op replicated in registers across all 512 threads (wave-uniform update);
// stack push is unconditional (speculative): the two target slots sit at or
// above the post-pop stack pointer on the leaf path, so they are dead unless
// this step is a parent. Row 64 of stack_s is scratch for the forced-leaf
// sp==64 edge case.
__global__ __launch_bounds__(512, 2)
void recur_kernel(const float* __restrict__ W1, const float* __restrict__ b1,
                  const float* __restrict__ W2, const float* __restrict__ b2,
                  const float* __restrict__ Wcomb, const float* __restrict__ bcomb,
                  const float* __restrict__ z,
                  float* __restrict__ Hrec, int* __restrict__ rowflag) {
    const int t = threadIdx.x;
    const int o = t & 255;
    const int half = t >> 8;               // 0 or 1
    __shared__ float stack_s[65 * 128];    // 32.5 KB (row 64 = scratch)
    __shared__ float hmid_s[256];
    __shared__ float part_s[2 * 256];
    __shared__ float w2r0_s[256];
    __shared__ float b1_s[256];
    __shared__ float bcomb_s[256];
    __shared__ float c0red_s[64];

    // resident weights (registers)
    float w1r[64];
    const float* w1p = W1 + (size_t)o * 128 + half * 64;
#pragma unroll
    for (int j = 0; j < 64; j++) w1r[j] = w1p[j];
    float wcr[128];
    const float* wcp = Wcomb + (size_t)o * 256 + half * 128;
#pragma unroll
    for (int j = 0; j < 128; j++) wcr[j] = wcp[j];

    if (half == 0) { w2r0_s[o] = W2[o]; b1_s[o] = b1[o]; bcomb_s[o] = bcomb[o]; }
    if (t < 128) { stack_s[t] = z[t]; rowflag[t] = -1; }
    const float b20 = b2[0];
    int sp = 1, op = 0;
    __syncthreads();

    for (int step = 0; step < NSTEP; step++) {
        const bool active = sp > 0;
        const int idx = active ? sp - 1 : 0;

        // phase 1: partial of hmid = lrelu(W1 @ node + b1)
        const float* nodep = stack_s + idx * 128 + half * 64;
        float a = 0.f;
#pragma unroll
        for (int j = 0; j < 64; j++) a += w1r[j] * nodep[j];
        part_s[half * 256 + o] = a;
        __syncthreads();                               // b1

        if (half == 0) {
            float pre = part_s[o] + part_s[256 + o] + b1_s[o];
            hmid_s[o] = pre > 0.f ? pre : 0.2f * pre;
        }
        __syncthreads();                               // b2

        // c0 partials (branch-decision dot), parallel with phase 2
        if (t < 64) {
            float s = 0.f;
#pragma unroll
            for (int m = 0; m < 4; m++) s += w2r0_s[t * 4 + m] * hmid_s[t * 4 + m];
            c0red_s[t] = s;
        }
        // record hmid for the batched vocab GEMM
        if (half == 0 && active) Hrec[(size_t)op * HID + o] = hmid_s[o];
        // phase 2: partial of [ll;rl] = Wcomb @ hmid + bcomb
        float a2 = 0.f;
        const float* hp = hmid_s + half * 128;
#pragma unroll
        for (int j = 0; j < 128; j++) a2 += wcr[j] * hp[j];
        part_s[half * 256 + o] = a2;
        __syncthreads();                               // b3

        // decision: computed redundantly by every thread (wave-uniform)
        float c0 = b20;
        const float4* cr4 = (const float4*)c0red_s;
#pragma unroll
        for (int m = 0; m < 16; m++) {
            float4 c = cr4[m];
            c0 += c.x + c.y + c.z + c.w;
        }
        const int par = (c0 > 0.f) && (sp <= 63) && active;
        if (t == 0 && active) rowflag[op] = par;

        // unconditional speculative push: ll -> idx, rl -> idx+1
        if (half == 0) {
            float v = part_s[o] + part_s[256 + o] + bcomb_s[o];
            stack_s[(idx + (o >> 7)) * 128 + (o & 127)] = v;
        }
        if (active) { sp = par ? sp + 1 : sp - 1; op++; }
        __syncthreads();                               // b4
    }
}

// ---------------- Co1 = Hrec @ W2[1:].T + b2[1:] ----------------
__global__ void co1_kernel(const float* __restrict__ Hrec, const float* __restrict__ W2,
                           const float* __restrict__ b2, float* __restrict__ Co1) {
    const int r = blockIdx.x;              // 0..127
    const int c = threadIdx.x;             // 0..255
    __shared__ float hs[256];
    hs[c] = Hrec[(size_t)r * HID + c];
    __syncthreads();
    float acc = b2[1 + c];
    const float4* w = (const float4*)(W2 + (size_t)(1 + c) * HID);
    const float4* h4 = (const float4*)hs;
#pragma unroll 8
    for (int k = 0; k < 64; k++) {
        float4 a = w[k], b = h4[k];
        acc += a.x * b.x + a.y * b.y + a.z * b.z + a.w * b.w;
    }
    Co1[r * HID + c] = acc;
}

// ---------------- zero unused out rows ----------------
__global__ void zero_rows(const int* __restrict__ rowflag, float* __restrict__ out) {
    const int r = blockIdx.x;
    if (rowflag[r] != -1) return;
    for (int q = threadIdx.x; q < VOC; q += 256) out[(size_t)r * VOC + q] = 0.f;
}

// ---------------- batched vocab matvecs: out[r] = Co1[r] @ Wx.T + bx ----------------
// One vocab column per thread; Co1 row-chunk (64 rows x 64 k) staged in LDS
// (broadcast reads); weight k-chunk = 16 independent float4 loads into regs.
__global__ __launch_bounds__(256, 2)
void value_kernel(const float* __restrict__ Co1, const int* __restrict__ rowflag,
                  const float* __restrict__ Wl, const float* __restrict__ bl,
                  const float* __restrict__ Wp, const float* __restrict__ bp,
                  float* __restrict__ out) {
    const int m = blockIdx.y;              // 0 = leaf (Wl), 1 = parent (Wp)
    const int t = threadIdx.x;
    const int v = blockIdx.x * 256 + t;    // 0..31999 (125 blocks x 256)
    const float* Wx = m ? Wp : Wl;
    const float* bx = m ? bp : bl;
    __shared__ int list[128];
    __shared__ int nrows_s;
    __shared__ float co_s[64 * 64];        // 16 KB
    if (t == 0) {
        int n = 0;
        for (int r = 0; r < 128; r++) if (rowflag[r] == m) list[n++] = r;
        nrows_s = n;
    }
    __syncthreads();
    const int nrows = nrows_s;
    const float bv = bx[v];
    const float4* w4 = (const float4*)(Wx + (size_t)v * HID);

    for (int rc = 0; rc < nrows; rc += 64) {
        const int nr = min(64, nrows - rc);
        float acc[64];
#pragma unroll
        for (int rr = 0; rr < 64; rr++) acc[rr] = 0.f;

        for (int kc = 0; kc < 4; kc++) {
            // stage Co1 chunk: 64 rows x 16 float4
#pragma unroll
            for (int q = 0; q < 4; q++) {
                const int qi = q * 256 + t;        // 0..1023
                const int rr = qi >> 4, kk4 = qi & 15;
                float4 val = make_float4(0.f, 0.f, 0.f, 0.f);
                if (rc + rr < nrows)
                    val = ((const float4*)(Co1 + (size_t)list[rc + rr] * HID + kc * 64))[kk4];
                ((float4*)co_s)[qi] = val;
            }
            // weight k-chunk into registers (16 independent loads)
            float4 w[16];
#pragma unroll
            for (int i = 0; i < 16; i++) w[i] = w4[kc * 16 + i];
            __syncthreads();
#pragma unroll
            for (int rr = 0; rr < 64; rr++) {
                const float4* c4 = (const float4*)co_s + rr * 16;
                float s = 0.f;
#pragma unroll
                for (int i = 0; i < 16; i++) {
                    float4 c = c4[i];
                    s += w[i].x * c.x + w[i].y * c.y + w[i].z * c.z + w[i].w * c.w;
                }
                acc[rr] += s;
            }
            __syncthreads();
        }
        for (int rr = 0; rr < nr; rr++)
            out[(size_t)list[rc + rr] * VOC + v] = acc[rr] + bv;
    }
}

extern "C" void kernel_launch(void* const* d_in, const int* in_sizes, int n_in,
                              void* d_out, int out_size, void* d_ws, size_t ws_size,
                              hipStream_t stream) {
    const float* embed = (const float*)d_in[0];
    const float* Wpar  = (const float*)d_in[1];
    const float* bpar  = (const float*)d_in[2];
    const float* Wmu   = (const float*)d_in[3];
    const float* bmu   = (const float*)d_in[4];
    const float* Wlv   = (const float*)d_in[5];
    const float* blv   = (const float*)d_in[6];
    const float* W1    = (const float*)d_in[7];
    const float* b1    = (const float*)d_in[8];
    const float* W2    = (const float*)d_in[9];
    const float* b2    = (const float*)d_in[10];
    const float* Wl    = (const float*)d_in[11];
    const float* bl    = (const float*)d_in[12];
    const float* Wp    = (const float*)d_in[13];
    const float* bp    = (const float*)d_in[14];
    const float* eps   = (const float*)d_in[15];
    const int*  values = (const int*)d_in[16];

    float* ws = (float*)d_ws;
    float* h      = ws;                    // 255*256 = 65280
    float* z      = ws + 65280;            // 128
    float* Wcomb  = ws + 65408;            // 65536
    float* bcomb  = ws + 130944;           // 256
    float* Hrec   = ws + 131200;           // 128*256 = 32768
    float* Co1    = ws + 163968;           // 32768
    int*   rowflag = (int*)(ws + 196736);  // 128
    float* out = (float*)d_out;

    // precompute collapsed push-weights (independent of encoder)
    wcomb_kernel<<<256, 256, 0, stream>>>(Wp, W2, b2, bp, Wcomb, bcomb);

    // encoder, level by level (7 .. 0)
    enc_level<<<128, 256, 0, stream>>>(embed, values, Wpar, bpar, h, 127, 1);
    enc_level<<< 64, 256, 0, stream>>>(embed, values, Wpar, bpar, h, 63, 0);
    enc_level<<< 32, 256, 0, stream>>>(embed, values, Wpar, bpar, h, 31, 0);
    enc_level<<< 16, 256, 0, stream>>>(embed, values, Wpar, bpar, h, 15, 0);
    enc_level<<<  8, 256, 0, stream>>>(embed, values, Wpar, bpar, h, 7, 0);
    enc_level<<<  4, 256, 0, stream>>>(embed, values, Wpar, bpar, h, 3, 0);
    enc_level<<<  2, 256, 0, stream>>>(embed, values, Wpar, bpar, h, 1, 0);
    enc_level<<<  1, 256, 0, stream>>>(embed, values, Wpar, bpar, h, 0, 0);

    root_kernel<<<1, 128, 0, stream>>>(h, Wmu, bmu, Wlv, blv, eps, out, z);

    recur_kernel<<<1, 512, 0, stream>>>(W1, b1, W2, b2, Wcomb, bcomb, z, Hrec, rowflag);

    co1_kernel<<<128, 256, 0, stream>>>(Hrec, W2, b2, Co1);
    zero_rows<<<128, 256, 0, stream>>>(rowflag, out);
    value_kernel<<<dim3(125, 2), 256, 0, stream>>>(Co1, rowflag, Wl, bl, Wp, bp, out);
}